// Round 1
// baseline (456.783 us; speedup 1.0000x reference)
//
#include <hip/hip_runtime.h>
#include <math.h>

namespace {

constexpr int B_   = 8;
constexpr int S_   = 8192;
constexpr int NROW = B_ * S_;      // 65536
constexpr int MC   = 48;           // model channels
constexpr int NOC  = 144;          // 3*48 (q,k,v)
constexpr int OF   = 88;           // output features (onset/frame)
constexpr int KW   = 31;           // window
constexpr int PADW = 15;
constexpr int F1   = 229;
constexpr int F2   = 136;          // 88 + 48

// ---------------- projection kernel: 64 rows/block, 256 threads -------------
// out oc layout: oc = o*16 + tx ; o in [0,3) -> q, [3,6) -> k, [6,9) -> v
template<int K, int KP>   // KP = K padded up to multiple of 16
__global__ __launch_bounds__(256) void proj_kernel(
    const float* __restrict__ x,      // [NROW][K]
    const float* __restrict__ Wq,     // [48][K]
    const float* __restrict__ Wk,
    const float* __restrict__ Wv,
    float* __restrict__ qo,           // [NROW][48]
    float* __restrict__ ko,
    float* __restrict__ vo)
{
    constexpr int XST = KP + 4;       // stride: (KP+4)%32==20 -> 2-way max (free)
    __shared__ float xs[64][XST];
    __shared__ float wls[NOC][20];    // 16-wide k-chunk, stride 20

    const int tid  = threadIdx.x;
    const int row0 = blockIdx.x * 64;

    for (int idx = tid; idx < 64 * KP; idx += 256) {
        int r = idx / KP, kk = idx - r * KP;
        xs[r][kk] = (kk < K) ? x[(size_t)(row0 + r) * K + kk] : 0.f;
    }

    const int tx = tid & 15;
    const int ty = tid >> 4;
    float acc[4][9];
    #pragma unroll
    for (int r = 0; r < 4; ++r)
        #pragma unroll
        for (int o = 0; o < 9; ++o) acc[r][o] = 0.f;

    for (int c = 0; c < KP / 16; ++c) {
        __syncthreads();
        for (int idx = tid; idx < NOC * 16; idx += 256) {
            int oc = idx >> 4, kk = idx & 15;
            int kg = c * 16 + kk;
            float val = 0.f;
            if (kg < K) {
                const float* W; int ocl;
                if (oc < 48)      { W = Wq; ocl = oc; }
                else if (oc < 96) { W = Wk; ocl = oc - 48; }
                else              { W = Wv; ocl = oc - 96; }
                val = W[ocl * K + kg];
            }
            wls[oc][kk] = val;
        }
        __syncthreads();
        #pragma unroll
        for (int k4 = 0; k4 < 16; k4 += 4) {
            float4 xv[4];
            float4 wv[9];
            #pragma unroll
            for (int r = 0; r < 4; ++r)
                xv[r] = *(const float4*)&xs[ty + 16 * r][c * 16 + k4];
            #pragma unroll
            for (int o = 0; o < 9; ++o)
                wv[o] = *(const float4*)&wls[o * 16 + tx][k4];
            #pragma unroll
            for (int r = 0; r < 4; ++r)
                #pragma unroll
                for (int o = 0; o < 9; ++o)
                    acc[r][o] += xv[r].x * wv[o].x + xv[r].y * wv[o].y
                               + xv[r].z * wv[o].z + xv[r].w * wv[o].w;
        }
    }

    #pragma unroll
    for (int r = 0; r < 4; ++r) {
        size_t row = (size_t)(row0 + ty + 16 * r);
        #pragma unroll
        for (int o = 0; o < 9; ++o) {
            int oc = o * 16 + tx;
            float val = acc[r][o];
            if (o < 3)      qo[row * MC + oc]        = val;
            else if (o < 6) ko[row * MC + (oc - 48)] = val;
            else            vo[row * MC + (oc - 96)] = val;
        }
    }
}

// -------- attention + LN + output-linear + sigmoid: 32 rows/block -----------
// thread tid = rl*8 + g  (rl: row 0..31, g: group 0..7); 8 lanes of a row are
// contiguous -> __shfl_xor width 8 for the LayerNorm reduction.
template<bool FIRST>
__global__ __launch_bounds__(256) void attn_kernel(
    const float* __restrict__ qb,     // [NROW][48]
    const float* __restrict__ kb,
    const float* __restrict__ vb,
    const float* __restrict__ rel,    // [48][31]
    const float* __restrict__ lng,    // [48]
    const float* __restrict__ lnb,
    const float* __restrict__ Wo,     // [88][48]
    const float* __restrict__ bo,     // [88]
    float* __restrict__ pred,         // [NROW][88] (sigmoid out)
    float* __restrict__ attn_out,     // [NROW][8][31]   (FIRST only)
    float* __restrict__ x2)           // [NROW][136]     (FIRST only)
{
    __shared__ float ks[62][49];
    __shared__ float vs[62][49];
    __shared__ float qs[32][49];
    __shared__ float rels[48][31];
    __shared__ float lns[32][52];
    __shared__ float wos[88][52];
    __shared__ float bos[88];
    __shared__ float lngs[48], lnbs[48];

    const int tid  = threadIdx.x;
    const int nblk = S_ / 32;
    const int bb   = blockIdx.x / nblk;
    const int st0  = (blockIdx.x - bb * nblk) * 32;
    const size_t base = (size_t)bb * S_;

    for (int idx = tid; idx < 62 * MC; idx += 256) {
        int rr = idx / MC, cc = idx - rr * MC;
        int si = st0 - PADW + rr;
        float kv = 0.f, vv = 0.f;
        if (si >= 0 && si < S_) {
            kv = kb[(base + si) * MC + cc];
            vv = vb[(base + si) * MC + cc];
        }
        ks[rr][cc] = kv;
        vs[rr][cc] = vv;
    }
    for (int idx = tid; idx < 32 * MC; idx += 256) {
        int rr = idx / MC, cc = idx - rr * MC;
        qs[rr][cc] = qb[(base + st0 + rr) * MC + cc];
    }
    for (int idx = tid; idx < MC * KW; idx += 256)
        rels[idx / KW][idx % KW] = rel[idx];
    for (int idx = tid; idx < OF * MC; idx += 256)
        wos[idx / MC][idx % MC] = Wo[idx];
    if (tid < OF) bos[tid] = bo[tid];
    if (tid >= 128 && tid < 128 + MC) {
        lngs[tid - 128] = lng[tid - 128];
        lnbs[tid - 128] = lnb[tid - 128];
    }
    __syncthreads();

    const int rl  = tid >> 3;
    const int g   = tid & 7;
    const int ch0 = g * 6;
    const size_t grow = base + st0 + rl;

    float qv[6];
    #pragma unroll
    for (int c = 0; c < 6; ++c) qv[c] = qs[rl][ch0 + c];

    float e[KW];
    float mx = -1e30f;
    for (int j = 0; j < KW; ++j) {
        float s = 0.f;
        #pragma unroll
        for (int c = 0; c < 6; ++c)
            s += qv[c] * (ks[rl + j][ch0 + c] + rels[ch0 + c][j]);
        e[j] = s;
        mx = fmaxf(mx, s);
    }
    float den = 0.f;
    #pragma unroll 1
    for (int j = 0; j < KW; ++j) { e[j] = __expf(e[j] - mx); den += e[j]; }
    float rden = 1.f / den;

    float o[6] = {0.f, 0.f, 0.f, 0.f, 0.f, 0.f};
    for (int j = 0; j < KW; ++j) {
        float aw = e[j] * rden;
        if constexpr (FIRST) attn_out[(grow * 8 + g) * KW + j] = aw;
        #pragma unroll
        for (int c = 0; c < 6; ++c)
            o[c] += aw * vs[rl + j][ch0 + c];
    }

    // LayerNorm over the 48 channels of this row (8 lanes x 6 each)
    float sum = o[0] + o[1] + o[2] + o[3] + o[4] + o[5];
    sum += __shfl_xor(sum, 1, 8);
    sum += __shfl_xor(sum, 2, 8);
    sum += __shfl_xor(sum, 4, 8);
    float mu = sum * (1.f / 48.f);
    float vr = 0.f;
    #pragma unroll
    for (int c = 0; c < 6; ++c) { float d = o[c] - mu; vr += d * d; }
    vr += __shfl_xor(vr, 1, 8);
    vr += __shfl_xor(vr, 2, 8);
    vr += __shfl_xor(vr, 4, 8);
    float rstd = rsqrtf(vr * (1.f / 48.f) + 1e-5f);
    #pragma unroll
    for (int c = 0; c < 6; ++c) {
        float y = (o[c] - mu) * rstd * lngs[ch0 + c] + lnbs[ch0 + c];
        lns[rl][ch0 + c] = y;
        if constexpr (FIRST) x2[grow * F2 + OF + ch0 + c] = y;
    }
    __syncthreads();

    // output linear (88) + sigmoid
    for (int idx = tid; idx < 32 * OF; idx += 256) {
        int rr = idx / OF, oc = idx - rr * OF;
        float s = bos[oc];
        #pragma unroll
        for (int kk = 0; kk < MC; kk += 4) {
            float4 a4 = *(const float4*)&lns[rr][kk];
            float4 w4 = *(const float4*)&wos[oc][kk];
            s += a4.x * w4.x + a4.y * w4.y + a4.z * w4.z + a4.w * w4.w;
        }
        s = 1.f / (1.f + __expf(-s));
        pred[(base + st0 + rr) * OF + oc] = s;
        if constexpr (FIRST) x2[(base + st0 + rr) * F2 + oc] = s;
    }
}

} // namespace

extern "C" void kernel_launch(void* const* d_in, const int* in_sizes, int n_in,
                              void* d_out, int out_size, void* d_ws, size_t ws_size,
                              hipStream_t stream) {
    const float* spec = (const float*)d_in[0];
    const float* Wq1  = (const float*)d_in[1];
    const float* Wk1  = (const float*)d_in[2];
    const float* Wv1  = (const float*)d_in[3];
    const float* rel1 = (const float*)d_in[4];
    const float* ln1g = (const float*)d_in[5];
    const float* ln1b = (const float*)d_in[6];
    const float* Wo   = (const float*)d_in[7];
    const float* bo   = (const float*)d_in[8];
    const float* Wq2  = (const float*)d_in[9];
    const float* Wk2  = (const float*)d_in[10];
    const float* Wv2  = (const float*)d_in[11];
    const float* rel2 = (const float*)d_in[12];
    const float* ln2g = (const float*)d_in[13];
    const float* ln2b = (const float*)d_in[14];
    const float* Wf   = (const float*)d_in[15];
    const float* bf   = (const float*)d_in[16];

    float* outf   = (float*)d_out;
    float* frame  = outf;                               // [NROW][88]
    float* onset  = outf + (size_t)NROW * OF;           // [NROW][88]
    float* attn_a = outf + (size_t)2 * NROW * OF;       // [NROW][8][31]

    float* wsf = (float*)d_ws;
    float* q1 = wsf;
    float* k1 = q1 + (size_t)NROW * MC;
    float* v1 = k1 + (size_t)NROW * MC;
    float* x2 = v1 + (size_t)NROW * MC;                 // [NROW][136]

    // phase 1
    proj_kernel<F1, 240><<<NROW / 64, 256, 0, stream>>>(spec, Wq1, Wk1, Wv1, q1, k1, v1);
    attn_kernel<true><<<NROW / 32, 256, 0, stream>>>(q1, k1, v1, rel1, ln1g, ln1b,
                                                     Wo, bo, onset, attn_a, x2);
    // phase 2 (reuse q1/k1/v1 buffers)
    proj_kernel<F2, 144><<<NROW / 64, 256, 0, stream>>>(x2, Wq2, Wk2, Wv2, q1, k1, v1);
    attn_kernel<false><<<NROW / 32, 256, 0, stream>>>(q1, k1, v1, rel2, ln2g, ln2b,
                                                      Wf, bf, frame, nullptr, nullptr);
}

// Round 2
// 255.904 us; speedup vs baseline: 1.7850x; 1.7850x over previous
//
#include <hip/hip_runtime.h>
#include <math.h>

namespace {

constexpr int B_   = 8;
constexpr int S_   = 8192;
constexpr int NROW = B_ * S_;      // 65536
constexpr int MC   = 48;           // model channels
constexpr int OF   = 88;           // output features (onset/frame)
constexpr int KW   = 31;           // window
constexpr int PADW = 15;
constexpr int F1   = 229;
constexpr int F2   = 136;          // 88 + 48

typedef __attribute__((ext_vector_type(8))) short bf16x8;
typedef __attribute__((ext_vector_type(4))) float f32x4;

__device__ inline unsigned short f2bf(float v) {
    unsigned u = __float_as_uint(v);
    unsigned r = (u + 0x7FFFu + ((u >> 16) & 1u)) >> 16;
    return (unsigned short)r;
}
__device__ inline float bf2f(unsigned short b) {
    return __uint_as_float((unsigned)b << 16);
}
__device__ inline unsigned pack2(unsigned short a, unsigned short b) {
    return (unsigned)a | ((unsigned)b << 16);
}

// ---- W prep: split W (q,k,v stacked as 144 rows) into bf16 hi/lo, chunk-major
// layout: out[chunk][half][oc][56]  with half-stride 8192, chunk-stride 16384 (ushorts)
__global__ void wprep_kernel(const float* __restrict__ Wq,
                             const float* __restrict__ Wk,
                             const float* __restrict__ Wv,
                             int K, int nch, unsigned short* __restrict__ out) {
    int idx = blockIdx.x * 256 + threadIdx.x;
    int kpad = nch * 32;
    int total = 144 * kpad;
    if (idx >= total) return;
    int oc = idx / kpad;
    int kg = idx - oc * kpad;
    int c  = kg >> 5, kk = kg & 31;
    float val = 0.f;
    if (kg < K) {
        const float* W = (oc < 48) ? Wq : (oc < 96 ? Wk : Wv);
        int ocl = (oc < 48) ? oc : (oc < 96 ? oc - 48 : oc - 96);
        val = W[ocl * K + kg];
    }
    unsigned short h = f2bf(val);
    unsigned short l = f2bf(val - bf2f(h));
    size_t base = (size_t)c * 16384 + (size_t)oc * 56 + kk;
    out[base]        = h;
    out[base + 8192] = l;
}

// ---- projection GEMM via MFMA, 3-term bf16 hi/lo split -----------------
// 64 rows/block, 256 threads (4 waves), each wave: 16 rows x 144 cols
template<int K, int NCH>
__global__ __launch_bounds__(256) void proj_mfma(
    const float* __restrict__ x,          // [NROW][K] fp32
    const unsigned short* __restrict__ wbuf, // prepacked hi/lo W chunks
    float* __restrict__ qo,               // [NROW][48]
    float* __restrict__ ko,
    float* __restrict__ vo)
{
    __shared__ __attribute__((aligned(16))) unsigned short Ah[64 * 56];
    __shared__ __attribute__((aligned(16))) unsigned short Al[64 * 56];
    __shared__ __attribute__((aligned(16))) unsigned short Bblk[16384];

    const int tid  = threadIdx.x;
    const int row0 = blockIdx.x * 64;
    const int lane = tid & 63;
    const int wm   = tid >> 6;

    f32x4 acc[9];
    #pragma unroll
    for (int nt = 0; nt < 9; ++nt) acc[nt] = f32x4{0.f, 0.f, 0.f, 0.f};

    const int arow = wm * 16 + (lane & 15);
    const int ak   = (lane >> 4) * 8;        // k-offset of this lane's fragment

    for (int c = 0; c < NCH; ++c) {
        // stage W chunk: 32768 B as 2048 uint4
        {
            const uint4* src = (const uint4*)(wbuf + (size_t)c * 16384);
            uint4* dst = (uint4*)Bblk;
            #pragma unroll
            for (int i = 0; i < 8; ++i)
                dst[tid + 256 * i] = src[tid + 256 * i];
        }
        // stage x chunk: 64 rows x 32 k, convert fp32 -> bf16 hi/lo
        const int kc = c * 32;
        #pragma unroll
        for (int i = 0; i < 4; ++i) {
            int idx = tid + 256 * i;          // 0..1023
            int r   = idx >> 4;               // 0..63
            int k2  = (idx & 15) * 2;         // 0,2,..,30
            int kg  = kc + k2;
            const float* xr = x + (size_t)(row0 + r) * K;
            float v0 = (kg     < K) ? xr[kg]     : 0.f;
            float v1 = (kg + 1 < K) ? xr[kg + 1] : 0.f;
            unsigned short h0 = f2bf(v0), h1 = f2bf(v1);
            unsigned short l0 = f2bf(v0 - bf2f(h0));
            unsigned short l1 = f2bf(v1 - bf2f(h1));
            *(unsigned*)&Ah[r * 56 + k2] = pack2(h0, h1);
            *(unsigned*)&Al[r * 56 + k2] = pack2(l0, l1);
        }
        __syncthreads();

        bf16x8 ah = *(const bf16x8*)&Ah[arow * 56 + ak];
        bf16x8 al = *(const bf16x8*)&Al[arow * 56 + ak];
        #pragma unroll
        for (int nt = 0; nt < 9; ++nt) {
            int bcol = nt * 16 + (lane & 15);
            bf16x8 bh = *(const bf16x8*)&Bblk[bcol * 56 + ak];
            bf16x8 bl = *(const bf16x8*)&Bblk[8192 + bcol * 56 + ak];
            acc[nt] = __builtin_amdgcn_mfma_f32_16x16x32_bf16(ah, bh, acc[nt], 0, 0, 0);
            acc[nt] = __builtin_amdgcn_mfma_f32_16x16x32_bf16(ah, bl, acc[nt], 0, 0, 0);
            acc[nt] = __builtin_amdgcn_mfma_f32_16x16x32_bf16(al, bh, acc[nt], 0, 0, 0);
        }
        __syncthreads();
    }

    // epilogue: D mapping col=lane&15, row=(lane>>4)*4+reg  [m89/m91]
    const int orow = row0 + wm * 16 + ((lane >> 4) << 2);
    const int ocol = lane & 15;
    #pragma unroll
    for (int nt = 0; nt < 9; ++nt) {
        float* dst = (nt < 3) ? qo : (nt < 6 ? ko : vo);
        int oc = (nt % 3) * 16 + ocol;
        #pragma unroll
        for (int rg = 0; rg < 4; ++rg)
            dst[(size_t)(orow + rg) * MC + oc] = acc[nt][rg];
    }
}

// -------- attention + LN + output-linear + sigmoid: 32 rows/block -----------
template<bool FIRST>
__global__ __launch_bounds__(256) void attn_kernel(
    const float* __restrict__ qb,     // [NROW][48]
    const float* __restrict__ kb,
    const float* __restrict__ vb,
    const float* __restrict__ rel,    // [48][31]
    const float* __restrict__ lng,    // [48]
    const float* __restrict__ lnb,
    const float* __restrict__ Wo,     // [88][48]
    const float* __restrict__ bo,     // [88]
    float* __restrict__ pred,         // [NROW][88] (sigmoid out)
    float* __restrict__ attn_out,     // [NROW][8][31]   (FIRST only)
    float* __restrict__ x2)           // [NROW][136]     (FIRST only)
{
    __shared__ float ks[62][49];
    __shared__ float vs[62][49];
    __shared__ float qs[32][49];
    __shared__ float rels[48][31];
    __shared__ float lns[32][52];
    __shared__ float wos[88][52];
    __shared__ float bos[88];
    __shared__ float lngs[48], lnbs[48];

    const int tid  = threadIdx.x;
    const int nblk = S_ / 32;
    const int bb   = blockIdx.x / nblk;
    const int st0  = (blockIdx.x - bb * nblk) * 32;
    const size_t base = (size_t)bb * S_;

    for (int idx = tid; idx < 62 * MC; idx += 256) {
        int rr = idx / MC, cc = idx - rr * MC;
        int si = st0 - PADW + rr;
        float kv = 0.f, vv = 0.f;
        if (si >= 0 && si < S_) {
            kv = kb[(base + si) * MC + cc];
            vv = vb[(base + si) * MC + cc];
        }
        ks[rr][cc] = kv;
        vs[rr][cc] = vv;
    }
    for (int idx = tid; idx < 32 * MC; idx += 256) {
        int rr = idx / MC, cc = idx - rr * MC;
        qs[rr][cc] = qb[(base + st0 + rr) * MC + cc];
    }
    for (int idx = tid; idx < MC * KW; idx += 256)
        rels[idx / KW][idx % KW] = rel[idx];
    for (int idx = tid; idx < OF * MC; idx += 256)
        wos[idx / MC][idx % MC] = Wo[idx];
    if (tid < OF) bos[tid] = bo[tid];
    if (tid >= 128 && tid < 128 + MC) {
        lngs[tid - 128] = lng[tid - 128];
        lnbs[tid - 128] = lnb[tid - 128];
    }
    __syncthreads();

    const int rl  = tid >> 3;
    const int g   = tid & 7;
    const int ch0 = g * 6;
    const size_t grow = base + st0 + rl;

    float qv[6];
    #pragma unroll
    for (int c = 0; c < 6; ++c) qv[c] = qs[rl][ch0 + c];

    float e[KW];
    float mx = -1e30f;
    for (int j = 0; j < KW; ++j) {
        float s = 0.f;
        #pragma unroll
        for (int c = 0; c < 6; ++c)
            s += qv[c] * (ks[rl + j][ch0 + c] + rels[ch0 + c][j]);
        e[j] = s;
        mx = fmaxf(mx, s);
    }
    float den = 0.f;
    #pragma unroll 1
    for (int j = 0; j < KW; ++j) { e[j] = __expf(e[j] - mx); den += e[j]; }
    float rden = 1.f / den;

    float o[6] = {0.f, 0.f, 0.f, 0.f, 0.f, 0.f};
    for (int j = 0; j < KW; ++j) {
        float aw = e[j] * rden;
        if constexpr (FIRST) attn_out[(grow * 8 + g) * KW + j] = aw;
        #pragma unroll
        for (int c = 0; c < 6; ++c)
            o[c] += aw * vs[rl + j][ch0 + c];
    }

    // LayerNorm over the 48 channels of this row (8 lanes x 6 each)
    float sum = o[0] + o[1] + o[2] + o[3] + o[4] + o[5];
    sum += __shfl_xor(sum, 1, 8);
    sum += __shfl_xor(sum, 2, 8);
    sum += __shfl_xor(sum, 4, 8);
    float mu = sum * (1.f / 48.f);
    float vr = 0.f;
    #pragma unroll
    for (int c = 0; c < 6; ++c) { float d = o[c] - mu; vr += d * d; }
    vr += __shfl_xor(vr, 1, 8);
    vr += __shfl_xor(vr, 2, 8);
    vr += __shfl_xor(vr, 4, 8);
    float rstd = rsqrtf(vr * (1.f / 48.f) + 1e-5f);
    #pragma unroll
    for (int c = 0; c < 6; ++c) {
        float y = (o[c] - mu) * rstd * lngs[ch0 + c] + lnbs[ch0 + c];
        lns[rl][ch0 + c] = y;
        if constexpr (FIRST) x2[grow * F2 + OF + ch0 + c] = y;
    }
    __syncthreads();

    // output linear (88) + sigmoid
    for (int idx = tid; idx < 32 * OF; idx += 256) {
        int rr = idx / OF, oc = idx - rr * OF;
        float s = bos[oc];
        #pragma unroll
        for (int kk = 0; kk < MC; kk += 4) {
            float4 a4 = *(const float4*)&lns[rr][kk];
            float4 w4 = *(const float4*)&wos[oc][kk];
            s += a4.x * w4.x + a4.y * w4.y + a4.z * w4.z + a4.w * w4.w;
        }
        s = 1.f / (1.f + __expf(-s));
        pred[(base + st0 + rr) * OF + oc] = s;
        if constexpr (FIRST) x2[(base + st0 + rr) * F2 + oc] = s;
    }
}

} // namespace

extern "C" void kernel_launch(void* const* d_in, const int* in_sizes, int n_in,
                              void* d_out, int out_size, void* d_ws, size_t ws_size,
                              hipStream_t stream) {
    const float* spec = (const float*)d_in[0];
    const float* Wq1  = (const float*)d_in[1];
    const float* Wk1  = (const float*)d_in[2];
    const float* Wv1  = (const float*)d_in[3];
    const float* rel1 = (const float*)d_in[4];
    const float* ln1g = (const float*)d_in[5];
    const float* ln1b = (const float*)d_in[6];
    const float* Wo   = (const float*)d_in[7];
    const float* bo   = (const float*)d_in[8];
    const float* Wq2  = (const float*)d_in[9];
    const float* Wk2  = (const float*)d_in[10];
    const float* Wv2  = (const float*)d_in[11];
    const float* rel2 = (const float*)d_in[12];
    const float* ln2g = (const float*)d_in[13];
    const float* ln2b = (const float*)d_in[14];
    const float* Wf   = (const float*)d_in[15];
    const float* bf   = (const float*)d_in[16];

    float* outf   = (float*)d_out;
    float* frame  = outf;                               // [NROW][88]
    float* onset  = outf + (size_t)NROW * OF;           // [NROW][88]
    float* attn_a = outf + (size_t)2 * NROW * OF;       // [NROW][8][31]

    float* wsf = (float*)d_ws;
    float* q1 = wsf;
    float* k1 = q1 + (size_t)NROW * MC;
    float* v1 = k1 + (size_t)NROW * MC;
    float* x2 = v1 + (size_t)NROW * MC;                 // [NROW][136]
    unsigned short* wbuf1 = (unsigned short*)(x2 + (size_t)NROW * F2);
    unsigned short* wbuf2 = wbuf1 + (size_t)8 * 16384;

    // prep weights (tiny)
    wprep_kernel<<<(144 * 8 * 32 + 255) / 256, 256, 0, stream>>>(Wq1, Wk1, Wv1, F1, 8, wbuf1);
    wprep_kernel<<<(144 * 5 * 32 + 255) / 256, 256, 0, stream>>>(Wq2, Wk2, Wv2, F2, 5, wbuf2);

    // phase 1
    proj_mfma<F1, 8><<<NROW / 64, 256, 0, stream>>>(spec, wbuf1, q1, k1, v1);
    attn_kernel<true><<<NROW / 32, 256, 0, stream>>>(q1, k1, v1, rel1, ln1g, ln1b,
                                                     Wo, bo, onset, attn_a, x2);
    // phase 2 (reuse q1/k1/v1 buffers)
    proj_mfma<F2, 5><<<NROW / 64, 256, 0, stream>>>(x2, wbuf2, q1, k1, v1);
    attn_kernel<false><<<NROW / 32, 256, 0, stream>>>(q1, k1, v1, rel2, ln2g, ln2b,
                                                      Wf, bf, frame, nullptr, nullptr);
}

// Round 3
// 182.937 us; speedup vs baseline: 2.4969x; 1.3989x over previous
//
#include <hip/hip_runtime.h>
#include <math.h>

namespace {

constexpr int B_   = 8;
constexpr int S_   = 8192;
constexpr int NROW = B_ * S_;      // 65536
constexpr int MC   = 48;           // model channels
constexpr int OF   = 88;           // output features (onset/frame)
constexpr int KW   = 31;           // window
constexpr int F1   = 229;
constexpr int F2   = 136;          // 88 + 48

typedef __attribute__((ext_vector_type(8))) short bf16x8;
typedef __attribute__((ext_vector_type(4))) float f32x4;

__device__ inline unsigned short f2bf(float v) {
    unsigned u = __float_as_uint(v);
    unsigned r = (u + 0x7FFFu + ((u >> 16) & 1u)) >> 16;
    return (unsigned short)r;
}
__device__ inline float bf2f(unsigned short b) {
    return __uint_as_float((unsigned)b << 16);
}
__device__ inline unsigned pack2(unsigned short a, unsigned short b) {
    return (unsigned)a | ((unsigned)b << 16);
}

// ---- W prep: split W (q,k,v stacked as 144 rows) into bf16 hi/lo, chunk-major
// layout: out[chunk][half][oc][56]  half-stride 8192, chunk-stride 16384 (ushorts)
__global__ void wprep_kernel(const float* __restrict__ Wq,
                             const float* __restrict__ Wk,
                             const float* __restrict__ Wv,
                             int K, int nch, unsigned short* __restrict__ out) {
    int idx = blockIdx.x * 256 + threadIdx.x;
    int kpad = nch * 32;
    int total = 144 * kpad;
    if (idx >= total) return;
    int oc = idx / kpad;
    int kg = idx - oc * kpad;
    int c  = kg >> 5, kk = kg & 31;
    float val = 0.f;
    if (kg < K) {
        const float* W = (oc < 48) ? Wq : (oc < 96 ? Wk : Wv);
        int ocl = (oc < 48) ? oc : (oc < 96 ? oc - 48 : oc - 96);
        val = W[ocl * K + kg];
    }
    unsigned short h = f2bf(val);
    unsigned short l = f2bf(val - bf2f(h));
    size_t base = (size_t)c * 16384 + (size_t)oc * 56 + kk;
    out[base]        = h;
    out[base + 8192] = l;
}

// ---- Wo/Wf prep: transpose to [96 n][64 k] bf16, hi plane then lo plane ----
__global__ void woprep_kernel(const float* __restrict__ W,  // [88][48]
                              unsigned short* __restrict__ out) {
    int idx = blockIdx.x * 256 + threadIdx.x;   // 96*64
    if (idx >= 96 * 64) return;
    int n = idx >> 6, k = idx & 63;
    float val = (n < OF && k < MC) ? W[n * MC + k] : 0.f;
    unsigned short h = f2bf(val);
    unsigned short l = f2bf(val - bf2f(h));
    out[idx]        = h;
    out[6144 + idx] = l;
}

// ---- projection GEMM via MFMA, 3-term bf16 hi/lo split -----------------
template<int K, int NCH>
__global__ __launch_bounds__(256) void proj_mfma(
    const float* __restrict__ x,
    const unsigned short* __restrict__ wbuf,
    float* __restrict__ qo, float* __restrict__ ko, float* __restrict__ vo)
{
    __shared__ __attribute__((aligned(16))) unsigned short Ah[64 * 56];
    __shared__ __attribute__((aligned(16))) unsigned short Al[64 * 56];
    __shared__ __attribute__((aligned(16))) unsigned short Bblk[16384];

    const int tid  = threadIdx.x;
    const int row0 = blockIdx.x * 64;
    const int lane = tid & 63;
    const int wm   = tid >> 6;

    f32x4 acc[9];
    #pragma unroll
    for (int nt = 0; nt < 9; ++nt) acc[nt] = f32x4{0.f, 0.f, 0.f, 0.f};

    const int arow = wm * 16 + (lane & 15);
    const int ak   = (lane >> 4) * 8;

    for (int c = 0; c < NCH; ++c) {
        {
            const uint4* src = (const uint4*)(wbuf + (size_t)c * 16384);
            uint4* dst = (uint4*)Bblk;
            #pragma unroll
            for (int i = 0; i < 8; ++i)
                dst[tid + 256 * i] = src[tid + 256 * i];
        }
        const int kc = c * 32;
        #pragma unroll
        for (int i = 0; i < 4; ++i) {
            int idx = tid + 256 * i;
            int r   = idx >> 4;
            int k2  = (idx & 15) * 2;
            int kg  = kc + k2;
            const float* xr = x + (size_t)(row0 + r) * K;
            float v0 = (kg     < K) ? xr[kg]     : 0.f;
            float v1 = (kg + 1 < K) ? xr[kg + 1] : 0.f;
            unsigned short h0 = f2bf(v0), h1 = f2bf(v1);
            unsigned short l0 = f2bf(v0 - bf2f(h0));
            unsigned short l1 = f2bf(v1 - bf2f(h1));
            *(unsigned*)&Ah[r * 56 + k2] = pack2(h0, h1);
            *(unsigned*)&Al[r * 56 + k2] = pack2(l0, l1);
        }
        __syncthreads();

        bf16x8 ah = *(const bf16x8*)&Ah[arow * 56 + ak];
        bf16x8 al = *(const bf16x8*)&Al[arow * 56 + ak];
        #pragma unroll
        for (int nt = 0; nt < 9; ++nt) {
            int bcol = nt * 16 + (lane & 15);
            bf16x8 bh = *(const bf16x8*)&Bblk[bcol * 56 + ak];
            bf16x8 bl = *(const bf16x8*)&Bblk[8192 + bcol * 56 + ak];
            acc[nt] = __builtin_amdgcn_mfma_f32_16x16x32_bf16(ah, bh, acc[nt], 0, 0, 0);
            acc[nt] = __builtin_amdgcn_mfma_f32_16x16x32_bf16(ah, bl, acc[nt], 0, 0, 0);
            acc[nt] = __builtin_amdgcn_mfma_f32_16x16x32_bf16(al, bh, acc[nt], 0, 0, 0);
        }
        __syncthreads();
    }

    const int orow = row0 + wm * 16 + ((lane >> 4) << 2);
    const int ocol = lane & 15;
    #pragma unroll
    for (int nt = 0; nt < 9; ++nt) {
        float* dst = (nt < 3) ? qo : (nt < 6 ? ko : vo);
        int oc = (nt % 3) * 16 + ocol;
        #pragma unroll
        for (int rg = 0; rg < 4; ++rg)
            dst[(size_t)(orow + rg) * MC + oc] = acc[nt][rg];
    }
}

// -------- attention + LN + MFMA-linear + sigmoid: 32 rows/block -------------
// thread tid = rl*8 + g for attention; wave-based MFMA epilogue.
template<bool FIRST>
__global__ __launch_bounds__(256, 4) void attn_kernel(
    const float* __restrict__ qb,     // [NROW][48]
    const float* __restrict__ kb,
    const float* __restrict__ vb,
    const float* __restrict__ rel,    // [48][31]
    const float* __restrict__ lng,
    const float* __restrict__ lnb,
    const unsigned short* __restrict__ wop,  // prepacked WoT hi/lo [2][96][64]
    const float* __restrict__ bo,     // [88]
    float* __restrict__ pred,         // [NROW][88]
    float* __restrict__ attn_out,     // [NROW][8][31]   (FIRST only)
    float* __restrict__ x2)           // [NROW][136]     (FIRST only)
{
    __shared__ __attribute__((aligned(16))) float ks[62 * 52];
    __shared__ __attribute__((aligned(16))) float vs[62 * 52];
    __shared__ __attribute__((aligned(16))) float relT[31 * 52];
    __shared__ __attribute__((aligned(16))) unsigned short lnbuf[2][32 * 48 + 64];
    __shared__ float bosL[96];
    __shared__ float lngs[48], lnbs[48];

    const int tid  = threadIdx.x;
    const int bb   = blockIdx.x >> 8;            // / 256 blocks per batch
    const int st0  = (blockIdx.x & 255) * 32;
    const size_t base = (size_t)bb * S_;

    // stage k/v (62 rows x 48 ch, float4)
    for (int idx = tid; idx < 744; idx += 256) {
        int rr = idx / 12, c4 = idx - rr * 12;
        int si = st0 - 15 + rr;
        float4 kv4 = {0.f, 0.f, 0.f, 0.f}, vv4 = {0.f, 0.f, 0.f, 0.f};
        if (si >= 0 && si < S_) {
            kv4 = *(const float4*)&kb[(base + si) * MC + c4 * 4];
            vv4 = *(const float4*)&vb[(base + si) * MC + c4 * 4];
        }
        *(float4*)&ks[rr * 52 + c4 * 4] = kv4;
        *(float4*)&vs[rr * 52 + c4 * 4] = vv4;
    }
    // rel transposed: relT[j][c]
    for (int idx = tid; idx < MC * KW; idx += 256) {
        int c = idx / KW, j = idx - c * KW;
        relT[j * 52 + c] = rel[idx];
    }
    if (tid < 96) bosL[tid] = (tid < OF) ? bo[tid] : 0.f;
    if (tid >= 128 && tid < 176) {
        lngs[tid - 128] = lng[tid - 128];
        lnbs[tid - 128] = lnb[tid - 128];
    }
    __syncthreads();

    const int rl  = tid >> 3;
    const int g   = tid & 7;
    const int ch0 = g * 6;
    const size_t grow = base + st0 + rl;

    const float* qr = qb + grow * MC + ch0;
    float2 q01 = *(const float2*)(qr);
    float2 q23 = *(const float2*)(qr + 2);
    float2 q45 = *(const float2*)(qr + 4);

    float e[KW];
    // q . rel  (init e)
    #pragma unroll
    for (int j = 0; j < KW; ++j) {
        const float* rp = &relT[j * 52 + ch0];
        float2 r01 = *(const float2*)(rp);
        float2 r23 = *(const float2*)(rp + 2);
        float2 r45 = *(const float2*)(rp + 4);
        e[j] = q01.x * r01.x + q01.y * r01.y + q23.x * r23.x
             + q23.y * r23.y + q45.x * r45.x + q45.y * r45.y;
    }
    // + q . k
    float mx = -1e30f;
    #pragma unroll
    for (int j = 0; j < KW; ++j) {
        const float* kp = &ks[(rl + j) * 52 + ch0];
        float2 k01 = *(const float2*)(kp);
        float2 k23 = *(const float2*)(kp + 2);
        float2 k45 = *(const float2*)(kp + 4);
        float s = e[j] + q01.x * k01.x + q01.y * k01.y + q23.x * k23.x
                       + q23.y * k23.y + q45.x * k45.x + q45.y * k45.y;
        e[j] = s;
        mx = fmaxf(mx, s);
    }
    float den = 0.f;
    #pragma unroll
    for (int j = 0; j < KW; ++j) { float t = __expf(e[j] - mx); e[j] = t; den += t; }
    float rden = 1.f / den;

    float o0 = 0.f, o1 = 0.f, o2 = 0.f, o3 = 0.f, o4 = 0.f, o5 = 0.f;
    #pragma unroll
    for (int j = 0; j < KW; ++j) {
        float aw = e[j] * rden;
        if constexpr (FIRST) attn_out[(grow * 8 + g) * KW + j] = aw;
        const float* vp = &vs[(rl + j) * 52 + ch0];
        float2 v01 = *(const float2*)(vp);
        float2 v23 = *(const float2*)(vp + 2);
        float2 v45 = *(const float2*)(vp + 4);
        o0 += aw * v01.x; o1 += aw * v01.y; o2 += aw * v23.x;
        o3 += aw * v23.y; o4 += aw * v45.x; o5 += aw * v45.y;
    }

    // LayerNorm across 48 channels (8 lanes x 6)
    float sum = o0 + o1 + o2 + o3 + o4 + o5;
    sum += __shfl_xor(sum, 1, 8);
    sum += __shfl_xor(sum, 2, 8);
    sum += __shfl_xor(sum, 4, 8);
    float mu = sum * (1.f / 48.f);
    float d0 = o0 - mu, d1 = o1 - mu, d2 = o2 - mu, d3 = o3 - mu, d4 = o4 - mu, d5 = o5 - mu;
    float vr = d0*d0 + d1*d1 + d2*d2 + d3*d3 + d4*d4 + d5*d5;
    vr += __shfl_xor(vr, 1, 8);
    vr += __shfl_xor(vr, 2, 8);
    vr += __shfl_xor(vr, 4, 8);
    float rstd = rsqrtf(vr * (1.f / 48.f) + 1e-5f);
    float y[6];
    y[0] = d0 * rstd * lngs[ch0]     + lnbs[ch0];
    y[1] = d1 * rstd * lngs[ch0 + 1] + lnbs[ch0 + 1];
    y[2] = d2 * rstd * lngs[ch0 + 2] + lnbs[ch0 + 2];
    y[3] = d3 * rstd * lngs[ch0 + 3] + lnbs[ch0 + 3];
    y[4] = d4 * rstd * lngs[ch0 + 4] + lnbs[ch0 + 4];
    y[5] = d5 * rstd * lngs[ch0 + 5] + lnbs[ch0 + 5];

    // stage y as bf16 hi/lo for the MFMA linear
    {
        unsigned short h[6], lo[6];
        #pragma unroll
        for (int c = 0; c < 6; ++c) {
            h[c]  = f2bf(y[c]);
            lo[c] = f2bf(y[c] - bf2f(h[c]));
        }
        unsigned* ph = (unsigned*)&lnbuf[0][rl * 48 + ch0];
        unsigned* pl = (unsigned*)&lnbuf[1][rl * 48 + ch0];
        ph[0] = pack2(h[0], h[1]);  ph[1] = pack2(h[2], h[3]);  ph[2] = pack2(h[4], h[5]);
        pl[0] = pack2(lo[0], lo[1]); pl[1] = pack2(lo[2], lo[3]); pl[2] = pack2(lo[4], lo[5]);
    }
    if constexpr (FIRST) {
        float* xp = x2 + grow * F2 + OF + ch0;
        *(float2*)(xp)     = float2{y[0], y[1]};
        *(float2*)(xp + 2) = float2{y[2], y[3]};
        *(float2*)(xp + 4) = float2{y[4], y[5]};
    }
    __syncthreads();

    // ---- MFMA output linear: [32x48] x [48x88] -> sigmoid -> pred ----
    const int l  = tid & 63;
    const int w  = tid >> 6;
    const int m  = w & 1;        // m-tile (rows m*16..m*16+15)
    const int ng = w >> 1;       // n-group (cols ng*48..)
    const int lr = l & 15;
    const int lk = (l >> 4) * 8;

    bf16x8 bh[3][2], bl[3][2];
    #pragma unroll
    for (int nt = 0; nt < 3; ++nt) {
        int ncol = (ng * 3 + nt) * 16 + lr;
        #pragma unroll
        for (int kc = 0; kc < 2; ++kc) {
            size_t boff = (size_t)ncol * 64 + kc * 32 + lk;
            bh[nt][kc] = *(const bf16x8*)&wop[boff];
            bl[nt][kc] = *(const bf16x8*)&wop[6144 + boff];
        }
    }
    const int arow = m * 16 + lr;
    bf16x8 ah0 = *(const bf16x8*)&lnbuf[0][arow * 48 + lk];
    bf16x8 al0 = *(const bf16x8*)&lnbuf[1][arow * 48 + lk];
    // kc=1: k = 32+lk; lanes with k>=48 read garbage but B rows are zero there
    bf16x8 ah1 = *(const bf16x8*)&lnbuf[0][arow * 48 + 32 + lk];
    bf16x8 al1 = *(const bf16x8*)&lnbuf[1][arow * 48 + 32 + lk];

    f32x4 acc[3];
    #pragma unroll
    for (int nt = 0; nt < 3; ++nt) acc[nt] = f32x4{0.f, 0.f, 0.f, 0.f};
    #pragma unroll
    for (int nt = 0; nt < 3; ++nt) {
        acc[nt] = __builtin_amdgcn_mfma_f32_16x16x32_bf16(ah0, bh[nt][0], acc[nt], 0, 0, 0);
        acc[nt] = __builtin_amdgcn_mfma_f32_16x16x32_bf16(ah0, bl[nt][0], acc[nt], 0, 0, 0);
        acc[nt] = __builtin_amdgcn_mfma_f32_16x16x32_bf16(al0, bh[nt][0], acc[nt], 0, 0, 0);
        acc[nt] = __builtin_amdgcn_mfma_f32_16x16x32_bf16(ah1, bh[nt][1], acc[nt], 0, 0, 0);
        acc[nt] = __builtin_amdgcn_mfma_f32_16x16x32_bf16(ah1, bl[nt][1], acc[nt], 0, 0, 0);
        acc[nt] = __builtin_amdgcn_mfma_f32_16x16x32_bf16(al1, bh[nt][1], acc[nt], 0, 0, 0);
    }

    const int rowo = st0 + m * 16 + ((l >> 4) << 2);
    #pragma unroll
    for (int nt = 0; nt < 3; ++nt) {
        int col = (ng * 3 + nt) * 16 + lr;
        if (col < OF) {
            float bias = bosL[col];
            #pragma unroll
            for (int rg = 0; rg < 4; ++rg) {
                float s  = acc[nt][rg] + bias;
                float sg = 1.f / (1.f + __expf(-s));
                size_t row = base + rowo + rg;
                pred[row * OF + col] = sg;
                if constexpr (FIRST) x2[row * F2 + col] = sg;
            }
        }
    }
}

} // namespace

extern "C" void kernel_launch(void* const* d_in, const int* in_sizes, int n_in,
                              void* d_out, int out_size, void* d_ws, size_t ws_size,
                              hipStream_t stream) {
    const float* spec = (const float*)d_in[0];
    const float* Wq1  = (const float*)d_in[1];
    const float* Wk1  = (const float*)d_in[2];
    const float* Wv1  = (const float*)d_in[3];
    const float* rel1 = (const float*)d_in[4];
    const float* ln1g = (const float*)d_in[5];
    const float* ln1b = (const float*)d_in[6];
    const float* Wo   = (const float*)d_in[7];
    const float* bo   = (const float*)d_in[8];
    const float* Wq2  = (const float*)d_in[9];
    const float* Wk2  = (const float*)d_in[10];
    const float* Wv2  = (const float*)d_in[11];
    const float* rel2 = (const float*)d_in[12];
    const float* ln2g = (const float*)d_in[13];
    const float* ln2b = (const float*)d_in[14];
    const float* Wf   = (const float*)d_in[15];
    const float* bf_  = (const float*)d_in[16];

    float* outf   = (float*)d_out;
    float* frame  = outf;
    float* onset  = outf + (size_t)NROW * OF;
    float* attn_a = outf + (size_t)2 * NROW * OF;

    float* wsf = (float*)d_ws;
    float* q1 = wsf;
    float* k1 = q1 + (size_t)NROW * MC;
    float* v1 = k1 + (size_t)NROW * MC;
    float* x2 = v1 + (size_t)NROW * MC;                 // [NROW][136]
    unsigned short* wbuf1 = (unsigned short*)(x2 + (size_t)NROW * F2);
    unsigned short* wbuf2 = wbuf1 + (size_t)8 * 16384;
    unsigned short* woP1  = wbuf2 + (size_t)5 * 16384;  // [2][96][64]
    unsigned short* woP2  = woP1 + 2 * 6144;

    wprep_kernel<<<(144 * 8 * 32 + 255) / 256, 256, 0, stream>>>(Wq1, Wk1, Wv1, F1, 8, wbuf1);
    wprep_kernel<<<(144 * 5 * 32 + 255) / 256, 256, 0, stream>>>(Wq2, Wk2, Wv2, F2, 5, wbuf2);
    woprep_kernel<<<24, 256, 0, stream>>>(Wo, woP1);
    woprep_kernel<<<24, 256, 0, stream>>>(Wf, woP2);

    proj_mfma<F1, 8><<<NROW / 64, 256, 0, stream>>>(spec, wbuf1, q1, k1, v1);
    attn_kernel<true><<<NROW / 32, 256, 0, stream>>>(q1, k1, v1, rel1, ln1g, ln1b,
                                                     woP1, bo, onset, attn_a, x2);
    proj_mfma<F2, 5><<<NROW / 64, 256, 0, stream>>>(x2, wbuf2, q1, k1, v1);
    attn_kernel<false><<<NROW / 32, 256, 0, stream>>>(q1, k1, v1, rel2, ln2g, ln2b,
                                                      woP2, bf_, frame, nullptr, nullptr);
}